// Round 15
// baseline (374.979 us; speedup 1.0000x reference)
//
#include <hip/hip_runtime.h>

// Block-circulant matmul via FFT, round 11 (resubmit — GPU acquisition timed
// out, kernel never measured): clamp VGPR to the 64 boundary.
// Round 10 CONFIRMED (VGPR 100->68, bc 163->137us, conflicts 3.3M->2.1M):
// unpack-free matmul Y = Hc*Z works as derived. Counters now show the binding
// constraint: VGPR=68 is 4 regs above the 64 occupancy step (waves/SIMD
// halves at 64/128/256) -> stuck at 4 waves/SIMD while LDS (32KiB) permits
// 5 blocks/CU = 20 waves/CU. Single change: __launch_bounds__(256, 4)
// clamps the allocator to 64 VGPRs (round 6 proved the attribute clamps;
// it spilled then because the live set was ~96 - now it is 68, a 4-reg
// shave the allocator can absorb by rematerialization).
// Predicted: VGPR 64, WRITE_SIZE stays ~131MB (no/trivial spill),
// occupancy 30->~40%, bc_kernel 137 -> ~110-118us.
// Algorithm (unchanged from round 10): rows packed z = x0*d + i*x1*d,
// 16 complex FFT-256/block, matmul per-column (thread t = column c, conj
// symmetry via sgn at load/store), one complex iFFT, Re->row0 / Im->row1.
// 2 barriers/block. LDS 32 KiB (swz XOR layout). Scale 1/256.

#define TWO_PI 6.283185307179586f

// XOR-swizzled LDS address: region r in 0..15, offset a in 0..255.
__device__ __forceinline__ int swz(int r, int a)
{
    return (r << 8) + (a ^ ((a >> 3) & 28) ^ ((r & 1) << 4));
}

// (vr,vi) *= e^{-i*SGN*alpha}, where (c,s) = (cos alpha, sin alpha)
template<int SGN>
__device__ __forceinline__ void twmul(float& vr, float& vi, float c, float s)
{
    float r = vr * c + SGN * (vi * s);
    float i = vi * c - SGN * (vr * s);
    vr = r; vi = i;
}

// Pair 1 = DIF stages D=64 and D=16, th = 2*pi*u/256.
// Elements: position u + 16m + 64k <-> register s = m + 4k. Complex in/out.
template<int SGN>
__device__ __forceinline__ void pair1(float* __restrict__ Ar, float* __restrict__ Ai,
                                      int reg, int u)
{
    float xr[16], xi[16];
#pragma unroll
    for (int s = 0; s < 16; ++s) {
        int a = swz(reg, u + 16 * s);
        xr[s] = Ar[a];
        xi[s] = Ai[a];
    }
    float su, cu;
    __sincosf((float)u * (TWO_PI / 256.f), &su, &cu);
    const float CM[4] = {1.f, 0.92387953f, 0.70710678f, 0.38268343f};
    const float SM[4] = {0.f, 0.38268343f, 0.70710678f, 0.92387953f};
    float c1[4], s1[4], c2[4], s2[4], c3[4], s3[4];
#pragma unroll
    for (int m = 0; m < 4; ++m) {
        c1[m] = cu * CM[m] - su * SM[m];
        s1[m] = su * CM[m] + cu * SM[m];
        c2[m] = c1[m] * c1[m] - s1[m] * s1[m];
        s2[m] = 2.f * c1[m] * s1[m];
        c3[m] = c2[m] * c1[m] - s2[m] * s1[m];
        s3[m] = s2[m] * c1[m] + c2[m] * s1[m];
    }
    // stage A (D=64): A_k = x[m+4k]
#pragma unroll
    for (int m = 0; m < 4; ++m) {
        float t0r = xr[m] + xr[m + 8],       t0i = xi[m] + xi[m + 8];
        float t1r = xr[m] - xr[m + 8],       t1i = xi[m] - xi[m + 8];
        float t2r = xr[m + 4] + xr[m + 12],  t2i = xi[m + 4] + xi[m + 12];
        float t3r = xr[m + 4] - xr[m + 12],  t3i = xi[m + 4] - xi[m + 12];
        xr[m] = t0r + t2r;  xi[m] = t0i + t2i;
        float v1r = t1r + SGN * t3i, v1i = t1i - SGN * t3r;
        float v2r = t0r - t2r,       v2i = t0i - t2i;
        float v3r = t1r - SGN * t3i, v3i = t1i + SGN * t3r;
        twmul<SGN>(v1r, v1i, c1[m], s1[m]);
        twmul<SGN>(v2r, v2i, c2[m], s2[m]);
        twmul<SGN>(v3r, v3i, c3[m], s3[m]);
        xr[m + 4]  = v1r; xi[m + 4]  = v1i;
        xr[m + 8]  = v2r; xi[m + 8]  = v2i;
        xr[m + 12] = v3r; xi[m + 12] = v3i;
    }
    // stage B (D=16): A_m = x[4k+m], twiddle angles 4th, 8th, 12th
    float cb1 = cu * cu - su * su, sb1 = 2.f * cu * su;                  // 2th
    { float c = cb1, s = sb1; cb1 = c * c - s * s; sb1 = 2.f * c * s; }  // 4th
    float cb2 = cb1 * cb1 - sb1 * sb1, sb2 = 2.f * cb1 * sb1;            // 8th
    float cb3 = cb2 * cb1 - sb2 * sb1, sb3 = sb2 * cb1 + cb2 * sb1;      // 12th
#pragma unroll
    for (int k = 0; k < 4; ++k) {
        int s0 = 4 * k;
        float t0r = xr[s0] + xr[s0 + 2],     t0i = xi[s0] + xi[s0 + 2];
        float t1r = xr[s0] - xr[s0 + 2],     t1i = xi[s0] - xi[s0 + 2];
        float t2r = xr[s0 + 1] + xr[s0 + 3], t2i = xi[s0 + 1] + xi[s0 + 3];
        float t3r = xr[s0 + 1] - xr[s0 + 3], t3i = xi[s0 + 1] - xi[s0 + 3];
        xr[s0] = t0r + t2r;  xi[s0] = t0i + t2i;
        float v1r = t1r + SGN * t3i, v1i = t1i - SGN * t3r;
        float v2r = t0r - t2r,       v2i = t0i - t2i;
        float v3r = t1r - SGN * t3i, v3i = t1i + SGN * t3r;
        twmul<SGN>(v1r, v1i, cb1, sb1);
        twmul<SGN>(v2r, v2i, cb2, sb2);
        twmul<SGN>(v3r, v3i, cb3, sb3);
        xr[s0 + 1] = v1r; xi[s0 + 1] = v1i;
        xr[s0 + 2] = v2r; xi[s0 + 2] = v2i;
        xr[s0 + 3] = v3r; xi[s0 + 3] = v3i;
    }
#pragma unroll
    for (int s = 0; s < 16; ++s) {
        int a = swz(reg, u + 16 * s);
        Ar[a] = xr[s]; Ai[a] = xi[s];
    }
}

// Pair 2 = DIF stages D=4 (compile-time twiddles) and D=1.
// Elements: position 16u + s (float4 LDS I/O, swizzle preserves 16B runs).
// STORE_REV: scatter outputs to rev4(position) (natural-order spectrum).
template<int SGN, bool STORE_REV>
__device__ __forceinline__ void pair2(float* __restrict__ Ar, float* __restrict__ Ai,
                                      int reg, int u)
{
    float xr[16], xi[16];
#pragma unroll
    for (int v = 0; v < 4; ++v) {
        int a = swz(reg, 16 * u + 4 * v);
        float4 vr = *(const float4*)(Ar + a);
        float4 vi = *(const float4*)(Ai + a);
        xr[4 * v] = vr.x; xr[4 * v + 1] = vr.y; xr[4 * v + 2] = vr.z; xr[4 * v + 3] = vr.w;
        xi[4 * v] = vi.x; xi[4 * v + 1] = vi.y; xi[4 * v + 2] = vi.z; xi[4 * v + 3] = vi.w;
    }
    // stage C (D=4): A_m = x[q+4m], twiddle (c,s) of pi*q*r/8
    const float CQ[4][4] = {
        {1.f, 1.f, 1.f, 1.f},
        {1.f, 0.92387953f, 0.70710678f, 0.38268343f},
        {1.f, 0.70710678f, 0.f, -0.70710678f},
        {1.f, 0.38268343f, -0.70710678f, -0.92387953f}};
    const float SQ[4][4] = {
        {0.f, 0.f, 0.f, 0.f},
        {0.f, 0.38268343f, 0.70710678f, 0.92387953f},
        {0.f, 0.70710678f, 1.f, 0.70710678f},
        {0.f, 0.92387953f, 0.70710678f, -0.38268343f}};
#pragma unroll
    for (int q = 0; q < 4; ++q) {
        float t0r = xr[q] + xr[q + 8],       t0i = xi[q] + xi[q + 8];
        float t1r = xr[q] - xr[q + 8],       t1i = xi[q] - xi[q + 8];
        float t2r = xr[q + 4] + xr[q + 12],  t2i = xi[q + 4] + xi[q + 12];
        float t3r = xr[q + 4] - xr[q + 12],  t3i = xi[q + 4] - xi[q + 12];
        xr[q] = t0r + t2r;  xi[q] = t0i + t2i;
        float v1r = t1r + SGN * t3i, v1i = t1i - SGN * t3r;
        float v2r = t0r - t2r,       v2i = t0i - t2i;
        float v3r = t1r - SGN * t3i, v3i = t1i + SGN * t3r;
        twmul<SGN>(v1r, v1i, CQ[q][1], SQ[q][1]);
        twmul<SGN>(v2r, v2i, CQ[q][2], SQ[q][2]);
        twmul<SGN>(v3r, v3i, CQ[q][3], SQ[q][3]);
        xr[q + 4]  = v1r; xi[q + 4]  = v1i;
        xr[q + 8]  = v2r; xi[q + 8]  = v2i;
        xr[q + 12] = v3r; xi[q + 12] = v3i;
    }
    // stage D (D=1): contiguous quads, no twiddle
#pragma unroll
    for (int g = 0; g < 4; ++g) {
        int s0 = 4 * g;
        float t0r = xr[s0] + xr[s0 + 2],     t1r = xr[s0] - xr[s0 + 2];
        float t2r = xr[s0 + 1] + xr[s0 + 3], t3r = xr[s0 + 1] - xr[s0 + 3];
        float t0i = xi[s0] + xi[s0 + 2],     t1i = xi[s0] - xi[s0 + 2];
        float t2i = xi[s0 + 1] + xi[s0 + 3], t3i = xi[s0 + 1] - xi[s0 + 3];
        xr[s0]     = t0r + t2r;  xi[s0]     = t0i + t2i;
        xr[s0 + 1] = t1r + SGN * t3i;  xi[s0 + 1] = t1i - SGN * t3r;
        xr[s0 + 2] = t0r - t2r;        xi[s0 + 2] = t0i - t2i;
        xr[s0 + 3] = t1r - SGN * t3i;  xi[s0 + 3] = t1i + SGN * t3r;
    }
    if (STORE_REV) {
        int q2 = (u >> 2) + ((u & 3) << 2);
#pragma unroll
        for (int s = 0; s < 16; ++s) {
            int dest = q2 + ((s >> 2) << 4) + ((s & 3) << 6);   // rev4(16u+s)
            int a = swz(reg, dest);
            Ar[a] = xr[s]; Ai[a] = xi[s];
        }
    } else {
#pragma unroll
        for (int v = 0; v < 4; ++v) {
            int a = swz(reg, 16 * u + 4 * v);
            *(float4*)(Ar + a) = make_float4(xr[4*v], xr[4*v+1], xr[4*v+2], xr[4*v+3]);
            *(float4*)(Ai + a) = make_float4(xi[4*v], xi[4*v+1], xi[4*v+2], xi[4*v+3]);
        }
    }
}

// Wc4[i][jc][f] = float4(Hc[f][i][2jc].re,.im, Hc[f][i][2jc+1].re,.im),
// f = 0..128 (pad 132), Hc = conj(FFT_256(W[i,j,:])). 270 KB in d_ws.
__global__ __launch_bounds__(256) void wfft_kernel(const float* __restrict__ W,
                                                   float* __restrict__ Wc4)
{
    __shared__ float wblk[256];
    __shared__ float tabc[256], tabs[256];
    int t   = threadIdx.x;                 // t = frequency f
    int blk = blockIdx.x;                  // blk = i*16 + j
    wblk[t] = W[blk * 256 + t];
    float s, c;
    __sincosf((float)t * (TWO_PI / 256.f), &s, &c);
    tabc[t] = c; tabs[t] = s;
    __syncthreads();
    if (t <= 128) {
        float ar = 0.f, ai = 0.f;
        for (int cc = 0; cc < 256; ++cc) {
            int idx = (t * cc) & 255;
            float wv = wblk[cc];
            ar = fmaf(wv, tabc[idx], ar);
            ai = fmaf(wv, tabs[idx], ai);
        }
        int i = blk >> 4, j = blk & 15;
        int flat = ((i * 8 + (j >> 1)) * 132 + t) * 4 + ((j & 1) << 1);
        Wc4[flat]     = ar;
        Wc4[flat + 1] = ai;
    }
}

__global__ __launch_bounds__(256, 4)
void bc_kernel(const float* __restrict__ x,
               const float* __restrict__ d,
               const float* __restrict__ bias,
               const float* __restrict__ Wc4,
               float* __restrict__ out)
{
    __shared__ float Ar[16 * 256], Ai[16 * 256];   // 32 KiB total -> 5 blocks/CU
    int t  = threadIdx.x;
    int b0 = blockIdx.x * 2;               // rows b0 (real part), b0+1 (imag part)
    int w = t >> 6, l = t & 63;
    int u = t & 15;
    int reg = t >> 4;                      // region = 4w + (l>>4), wave-owned

    // ---- load: z_j = x0_j*d + i*x1_j*d, wave w loads its own regions 4w..4w+3
    const float4* d4 = (const float4*)d;
    const float4* x40 = (const float4*)(x + (size_t)b0 * 4096);
    const float4* x41 = (const float4*)(x + (size_t)(b0 + 1) * 4096);
#pragma unroll
    for (int it = 0; it < 4; ++it) {
        int idx = 256 * w + 64 * it + l;
        float4 dv = d4[idx];
        float4 v0 = x40[idx];
        float4 v1 = x41[idx];
        int a = swz(4 * w + it, 4 * l);
        *(float4*)(Ar + a) = make_float4(v0.x * dv.x, v0.y * dv.y, v0.z * dv.z, v0.w * dv.w);
        *(float4*)(Ai + a) = make_float4(v1.x * dv.x, v1.y * dv.y, v1.z * dv.z, v1.w * dv.w);
    }
    // no barrier: regions are wave-private, DS ops in-order within a wave

    pair1<1>(Ar, Ai, reg, u);
    pair2<1, true>(Ar, Ai, reg, u);            // scatter -> natural-order spectrum
    __syncthreads();                           // BAR 1: matmul reads cross-wave

    // ---- frequency matmul, unpack-free: thread t owns column c = t.
    // Y[i][c] = sum_j Hc[i][j][c] * Z[j][c]; for c>128 use conj symmetry
    // Hc(c) = conj(Hc(256-c)), applied via zi *= sgn at load, yi *= sgn at
    // store (y = conj(sum h*conj(z)) identity). Column c is read AND written
    // only by this thread -> no barrier inside the matmul.
    {
        int c    = t;
        int fidx = (c <= 128) ? c : 256 - c;   // 0..128
        float sgn = (c <= 128) ? 1.f : -1.f;
        float zr[16], zi[16];
#pragma unroll
        for (int j = 0; j < 16; ++j) {
            zr[j] = Ar[swz(j, c)];
            zi[j] = Ai[swz(j, c)] * sgn;
        }
        const float4* wb = (const float4*)Wc4;
#pragma unroll
        for (int i = 0; i < 16; ++i) {
            float yr = 0.f, yi = 0.f;
#pragma unroll
            for (int jc = 0; jc < 8; ++jc) {
                float4 wv = wb[(i * 8 + jc) * 132 + fidx];
                int j0 = 2 * jc;
                yr = fmaf(zr[j0], wv.x, yr);   yr = fmaf(-zi[j0], wv.y, yr);
                yi = fmaf(zr[j0], wv.y, yi);   yi = fmaf(zi[j0], wv.x, yi);
                yr = fmaf(zr[j0+1], wv.z, yr); yr = fmaf(-zi[j0+1], wv.w, yr);
                yi = fmaf(zr[j0+1], wv.w, yi); yi = fmaf(zi[j0+1], wv.z, yi);
            }
            Ar[swz(i, c)] = yr;
            Ai[swz(i, c)] = yi * sgn;
        }
    }
    __syncthreads();                           // BAR 2: inverse reads cross-wave

    pair1<-1>(Ar, Ai, reg, u);
    pair2<-1, false>(Ar, Ai, reg, u);          // full complex out, contiguous store
    // no barrier: gather below reads own-wave regions only

    // ---- store: gather rev4 positions; Re -> row b0, Im -> row b0+1
    const float4* b4 = (const float4*)bias;
    float* o0 = out + (size_t)b0 * 4096;
    float* o1 = out + (size_t)(b0 + 1) * 4096;
    int dbase = ((l >> 4) & 3) + (((l >> 2) & 3) << 2) + ((l & 3) << 4);
#pragma unroll
    for (int it = 0; it < 4; ++it) {
        int idx = 256 * w + 64 * it + l;
        int rg  = 4 * w + it;
        float v0[4], v1[4];
#pragma unroll
        for (int e = 0; e < 4; ++e) {
            int a = swz(rg, dbase + (e << 6));   // rev4(4l+e)
            v0[e] = Ar[a];
            v1[e] = Ai[a];
        }
        float4 bv = b4[idx];
        float4 ov0, ov1;
        ov0.x = v0[0] * (1.f / 256.f) + bv.x;
        ov0.y = v0[1] * (1.f / 256.f) + bv.y;
        ov0.z = v0[2] * (1.f / 256.f) + bv.z;
        ov0.w = v0[3] * (1.f / 256.f) + bv.w;
        ov1.x = v1[0] * (1.f / 256.f) + bv.x;
        ov1.y = v1[1] * (1.f / 256.f) + bv.y;
        ov1.z = v1[2] * (1.f / 256.f) + bv.z;
        ov1.w = v1[3] * (1.f / 256.f) + bv.w;
        ((float4*)o0)[idx] = ov0;
        ((float4*)o1)[idx] = ov1;
    }
}

extern "C" void kernel_launch(void* const* d_in, const int* in_sizes, int n_in,
                              void* d_out, int out_size, void* d_ws, size_t ws_size,
                              hipStream_t stream)
{
    const float* x    = (const float*)d_in[0];   // (8192, 4096)
    const float* W    = (const float*)d_in[1];   // (16, 16, 256)
    const float* d    = (const float*)d_in[2];   // (4096,)
    const float* bias = (const float*)d_in[3];   // (4096,)
    float* out = (float*)d_out;
    float* Wc4 = (float*)d_ws;                   // [16][8][132] float4 = 270 KB

    wfft_kernel<<<256, 256, 0, stream>>>(W, Wc4);
    bc_kernel<<<4096, 256, 0, stream>>>(x, d, bias, Wc4, out);
}